// Round 5
// baseline (1868.141 us; speedup 1.0000x reference)
//
#include <hip/hip_runtime.h>

// CG-SENSE: B=4, C=16, H=W=384. fp32. x lives in d_out (float2 == [.,2]).
// FFT-384 = wave-synchronous four-step: in-register FFT-12, per-lane twiddle,
// cross-lane FFT-32 via ds_swizzle. Unscramble through LDS, 13-stride layout:
// natural index w lives at LDS offset offmap(w) = w + w/12.
// Col kernels: 12-column panels, 384 threads (4 blocks/CU), float4 staging.
// k_row_inv_acc: software-pipelined across coils (next tmp loads in flight
// during current FFT — issued before the lgkm fences so the clobber keeps them).

#define Bn 4
#define Cn 16
#define Hn 384
#define Wn 384
#define NPIX (Hn*Wn)
#define TPB 256
#define CTPB 384
#define NCOL 12
#define TOLF 1e-10f
#define NITER 10
#define RED_BLKS 72
#define RPITCH 416   // row-kernel LDS pitch (float2)
#define CPITCH 417   // col-kernel pitch (float2): 834 words % 32 == 2

__device__ __forceinline__ float2 cadd(float2 a, float2 b){ return make_float2(a.x+b.x, a.y+b.y); }
__device__ __forceinline__ float2 csub(float2 a, float2 b){ return make_float2(a.x-b.x, a.y-b.y); }
__device__ __forceinline__ float2 cmulf(float2 a, float2 b){
  return make_float2(a.x*b.x - a.y*b.y, a.x*b.y + a.y*b.x);
}

// wave-local LDS fence: DS ops are in-order per wave; write->fence->read within
// a wave is safe without s_barrier.
__device__ __forceinline__ void wave_fence(){ asm volatile("s_waitcnt lgkmcnt(0)" ::: "memory"); }

template<int IMM>
__device__ __forceinline__ float2 shx(float2 v){
  int x = __builtin_amdgcn_ds_swizzle(__float_as_int(v.x), IMM);
  int y = __builtin_amdgcn_ds_swizzle(__float_as_int(v.y), IMM);
  return make_float2(__int_as_float(x), __int_as_float(y));
}

__device__ __forceinline__ int rev5(int x){
  return ((x&1)<<4) | ((x&2)<<2) | (x&4) | ((x&8)>>2) | ((x&16)>>4);
}

__device__ __forceinline__ int offmap(int w){ return w + ((w*683)>>13); }  // w + w/12, w<384

// ---- in-register FFT-12 (natural in, natural out). 12 = 3x4 ----
template<int DIR>
__device__ __forceinline__ void fft12(float2* v)
{
  const float S3 = (DIR<0) ? -0.86602540378443864676f : 0.86602540378443864676f;
  const float sg = (DIR<0) ? -1.f : 1.f;
  float2 t[4][3];
#pragma unroll
  for (int b = 0; b < 4; ++b) {
    float2 a0 = v[b], a1 = v[4+b], a2 = v[8+b];
    float2 s = cadd(a1,a2), d = csub(a1,a2);
    float2 mm = make_float2(a0.x - 0.5f*s.x, a0.y - 0.5f*s.y);
    float2 e  = make_float2(-d.y*S3, d.x*S3);
    t[b][0] = cadd(a0,s);
    t[b][1] = cadd(mm,e);
    t[b][2] = csub(mm,e);
  }
  const float2 w1  = make_float2(0.86602540378443864676f, sg*0.5f);
  const float2 w2  = make_float2(0.5f, sg*0.86602540378443864676f);
  const float2 w3  = make_float2(0.f, sg);
  const float2 w4t = make_float2(-0.5f, sg*0.86602540378443864676f);
  const float2 w6  = make_float2(-1.f, 0.f);
  t[1][1] = cmulf(t[1][1], w1);  t[1][2] = cmulf(t[1][2], w2);
  t[2][1] = cmulf(t[2][1], w2);  t[2][2] = cmulf(t[2][2], w4t);
  t[3][1] = cmulf(t[3][1], w3);  t[3][2] = cmulf(t[3][2], w6);
#pragma unroll
  for (int c = 0; c < 3; ++c) {
    float2 e = cadd(t[0][c], t[2][c]);
    float2 f = csub(t[0][c], t[2][c]);
    float2 g = cadd(t[1][c], t[3][c]);
    float2 h = csub(t[1][c], t[3][c]);
    float2 ih = (DIR<0) ? make_float2(h.y, -h.x) : make_float2(-h.y, h.x);
    v[c]   = cadd(e,g);
    v[c+3] = cadd(f,ih);
    v[c+6] = csub(e,g);
    v[c+9] = csub(f,ih);
  }
}

// ---- cross-lane FFT-32 over lanes (natural in, bit-reversed lane out) ----
template<int DIR>
__device__ __forceinline__ void fft32_lanes(float2* v, int li)
{
  const float c2pi = (DIR<0) ? -6.2831853071795864769f : 6.2831853071795864769f;
  const float sg   = (DIR<0) ? -1.f : 1.f;
  float s, c;
  __sincosf(c2pi*(1.f/32.f)*(float)(li&15), &s, &c); float2 wA = make_float2(c,s);
  __sincosf(c2pi*(1.f/16.f)*(float)(li&7),  &s, &c); float2 wB = make_float2(c,s);
  __sincosf(c2pi*(1.f/ 8.f)*(float)(li&3),  &s, &c); float2 wC = make_float2(c,s);
  bool bA = li & 16, bB = li & 8, bC = li & 4, bD = li & 2, bE = li & 1;
#pragma unroll
  for (int k = 0; k < 12; ++k) {
    float2 a = v[k], o;
    o = shx<0x401F>(a); a = bA ? cmulf(csub(o,a), wA) : cadd(a,o);
    o = shx<0x201F>(a); a = bB ? cmulf(csub(o,a), wB) : cadd(a,o);
    o = shx<0x101F>(a); a = bC ? cmulf(csub(o,a), wC) : cadd(a,o);
    o = shx<0x081F>(a);
    { float2 su = cadd(a,o), d = csub(o,a);
      float2 dw = bE ? make_float2(-sg*d.y, sg*d.x) : d;
      a = bD ? dw : su; }
    o = shx<0x041F>(a); a = bE ? csub(o,a) : cadd(a,o);
    v[k] = a;
  }
}

// Full 384-pt FFT. In: reg k = x[32k+li]. Out: reg k1 = X[k1 + 12*rev5(li)].
template<int DIR>
__device__ __forceinline__ void fft384(float2* v, int li)
{
  fft12<DIR>(v);
  const float c2pi = (DIR<0) ? -6.2831853071795864769f : 6.2831853071795864769f;
  float s, c;
  __sincosf(c2pi*(1.f/384.f)*(float)li, &s, &c);
  float2 W = make_float2(c,s), cw = W;
#pragma unroll
  for (int k = 1; k < 12; ++k) { v[k] = cmulf(v[k], cw); cw = cmulf(cw, W); }
  fft32_lanes<DIR>(v, li);
}

// ---------------- FFT kernels ----------------

// tmp[b,c,h,:] = FFT_w( S[b,c,h,:] * p[b,h,:] )   (unnormalized fwd)
__global__ __launch_bounds__(TPB) void k_row_fwd(
    const float2* __restrict__ p, const float* __restrict__ Sre,
    const float* __restrict__ Sim, float2* __restrict__ tmp)
{
  __shared__ float2 lbuf[8*RPITCH];
  int tid = threadIdx.x;
  int wave = tid>>6, lane = tid&63, sub = lane>>5, li = lane&31;
  int row = wave*2 + sub;
  int tile = blockIdx.x % (Hn/8);
  int bc   = blockIdx.x / (Hn/8);
  int b = bc / Cn;
  int h = tile*8 + row;
  size_t gbase = (size_t)bc*NPIX + (size_t)h*Wn;
  size_t pbase = (size_t)b*NPIX + (size_t)h*Wn;

  float2 v[12];
#pragma unroll
  for (int k = 0; k < 12; ++k) {
    int w = 32*k + li;
    float2 pv = p[pbase + w];
    float sr = Sre[gbase + w], si = Sim[gbase + w];
    v[k] = make_float2(sr*pv.x - si*pv.y, sr*pv.y + si*pv.x);
  }
  fft384<-1>(v, li);
  int m = rev5(li);
  float2* lrow = lbuf + row*RPITCH;
#pragma unroll
  for (int k = 0; k < 12; ++k) lrow[13*m + k] = v[k];
  wave_fence();
#pragma unroll
  for (int k = 0; k < 12; ++k) {
    int w = 32*k + li;
    tmp[gbase + w] = lrow[offmap(w)];
  }
}

// partial[g,b] = sum_{c in group g} conj(S[b,c]) * IFFT_w(tmp[b,c])
// Software-pipelined: next coil's tmp loads issued before current FFT/fences.
template<int CPGt>
__global__ __launch_bounds__(TPB) void k_row_inv_acc(
    const float2* __restrict__ tmp, const float* __restrict__ Sre,
    const float* __restrict__ Sim, float2* __restrict__ partial)
{
  const int GRPt = Cn/CPGt;
  __shared__ float2 lbuf[8*RPITCH];
  int tid = threadIdx.x;
  int wave = tid>>6, lane = tid&63, sub = lane>>5, li = lane&31;
  int row = wave*2 + sub;
  int tile = blockIdx.x % (Hn/8);
  int rest = blockIdx.x / (Hn/8);
  int g = rest % GRPt;
  int b = rest / GRPt;
  int h = tile*8 + row;
  int m = rev5(li);
  float2* lrow = lbuf + row*RPITCH;

  size_t gbase0 = ((size_t)b*Cn + g*CPGt)*NPIX + (size_t)h*Wn;
  float2 vc[12], vn[12];
#pragma unroll
  for (int k = 0; k < 12; ++k) vc[k] = tmp[gbase0 + 32*k + li];

  float2 acc[12];
#pragma unroll
  for (int k = 0; k < 12; ++k) acc[k] = make_float2(0.f, 0.f);

  for (int j = 0; j < CPGt; ++j) {
    size_t gb = gbase0 + (size_t)j*NPIX;
    if (j + 1 < CPGt) {               // prefetch next coil BEFORE any fence
      size_t gbn = gb + NPIX;
#pragma unroll
      for (int k = 0; k < 12; ++k) vn[k] = tmp[gbn + 32*k + li];
    }
    fft384<1>(vc, li);
    wave_fence();                     // WAR: prior gather reads drained
#pragma unroll
    for (int k = 0; k < 12; ++k) lrow[13*m + k] = vc[k];
    wave_fence();                     // RAW: writes visible before gather
#pragma unroll
    for (int k = 0; k < 12; ++k) {
      int w = 32*k + li;
      float2 u = lrow[offmap(w)];
      float sr = Sre[gb + w], si = Sim[gb + w];
      acc[k].x += sr*u.x + si*u.y;
      acc[k].y += sr*u.y - si*u.x;
    }
    if (j + 1 < CPGt) {
#pragma unroll
      for (int k = 0; k < 12; ++k) vc[k] = vn[k];
    }
  }
  size_t pbase = ((size_t)g*Bn + b)*NPIX + (size_t)h*Wn;
#pragma unroll
  for (int k = 0; k < 12; ++k) partial[pbase + 32*k + li] = acc[k];
}

// lane-permuted scaled mask + scal zeroing.
// maskP[((b*Wn+w)*32+li)*12+k] = mask[b][k+12*rev5(li)][w]/NPIX
__global__ __launch_bounds__(TPB) void k_maskp(
    const float* __restrict__ mask, float* __restrict__ maskP,
    float* __restrict__ scal)
{
  int idx = blockIdx.x*TPB + threadIdx.x;
  if (blockIdx.x == 0 && threadIdx.x < 96) scal[threadIdx.x] = 0.0f;
  if (idx >= Bn*NPIX) return;
  int k = idx % 12; int t = idx / 12;
  int li = t & 31; t >>= 5;
  int w = t % Wn;  int b = t / Wn;
  maskP[idx] = mask[((size_t)b*Hn + (k + 12*rev5(li)))*Wn + w] * (1.0f/(float)NPIX);
}

// column pass: fwd FFT_h, * maskP, inv FFT_h. 12 columns, 384 threads.
__global__ __launch_bounds__(CTPB) void k_col_full(
    float2* __restrict__ tmp, const float* __restrict__ maskP)
{
  __shared__ float2 dbuf[NCOL*CPITCH];   // 40032 B
  int tid = threadIdx.x;
  int wave = tid>>6, lane = tid&63, sub = lane>>5, li = lane&31;
  int col = wave*2 + sub;
  int tile = blockIdx.x % (Wn/NCOL);
  int bc   = blockIdx.x / (Wn/NCOL);
  int b = bc / Cn;
  int w0 = tile*NCOL;
  size_t tbase = (size_t)bc*NPIX;

  // stage in: float4 = 2 float2 (w-pair). 2304 pairs = 384 thr x 6.
#pragma unroll
  for (int t = 0; t < 6; ++t) {
    int pi = tid + CTPB*t;
    int h = pi / 6, wp = pi - 6*h;
    float4 q = *(const float4*)(tmp + tbase + (size_t)h*Wn + w0 + 2*wp);
    int off = offmap(h);
    dbuf[(2*wp  )*CPITCH + off] = make_float2(q.x, q.y);
    dbuf[(2*wp+1)*CPITCH + off] = make_float2(q.z, q.w);
  }
  __syncthreads();

  float2* drow = dbuf + col*CPITCH;
  int w = w0 + col;
  int m = rev5(li);
  // issue maskP loads before the forward FFT (independent)
  const float4* mp4 = (const float4*)(maskP + (((size_t)b*Wn + w)*32 + li)*12);
  float4 m0 = mp4[0], m1 = mp4[1], m2 = mp4[2];
  float2 v[12];
#pragma unroll
  for (int k = 0; k < 12; ++k) v[k] = drow[offmap(32*k + li)];
  fft384<-1>(v, li);
  float mk[12] = {m0.x,m0.y,m0.z,m0.w, m1.x,m1.y,m1.z,m1.w, m2.x,m2.y,m2.z,m2.w};
#pragma unroll
  for (int k = 0; k < 12; ++k) v[k] = make_float2(v[k].x*mk[k], v[k].y*mk[k]);
  wave_fence();
#pragma unroll
  for (int k = 0; k < 12; ++k) drow[13*m + k] = v[k];    // unscramble store
  wave_fence();
#pragma unroll
  for (int k = 0; k < 12; ++k) v[k] = drow[offmap(32*k + li)];  // natural reload
  fft384<1>(v, li);
  wave_fence();
#pragma unroll
  for (int k = 0; k < 12; ++k) drow[13*m + k] = v[k];
  __syncthreads();

#pragma unroll
  for (int t = 0; t < 6; ++t) {
    int pi = tid + CTPB*t;
    int h = pi / 6, wp = pi - 6*h;
    int off = offmap(h);
    float2 a = dbuf[(2*wp  )*CPITCH + off];
    float2 bq = dbuf[(2*wp+1)*CPITCH + off];
    *(float4*)(tmp + tbase + (size_t)h*Wn + w0 + 2*wp) = make_float4(a.x, a.y, bq.x, bq.y);
  }
}

// rhs column pass: stage y*mask*(1/384), inverse column FFT only. 12 cols, 384 thr.
__global__ __launch_bounds__(CTPB) void k_col_rhs(
    const float* __restrict__ yre, const float* __restrict__ yim,
    const float* __restrict__ mask, float2* __restrict__ tmp)
{
  __shared__ float2 dbuf[NCOL*CPITCH];
  int tid = threadIdx.x;
  int wave = tid>>6, lane = tid&63, sub = lane>>5, li = lane&31;
  int col = wave*2 + sub;
  int tile = blockIdx.x % (Wn/NCOL);
  int bc   = blockIdx.x / (Wn/NCOL);
  int b = bc / Cn;
  int w0 = tile*NCOL;
  size_t tbase = (size_t)bc*NPIX;
  size_t mbase = (size_t)b*NPIX;

  // stage in: quads of 4 w's. 1152 quads = 384 thr x 3.
#pragma unroll
  for (int t = 0; t < 3; ++t) {
    int qi = tid + CTPB*t;
    int h = qi / 3, wq = qi - 3*h;
    size_t gi = (size_t)h*Wn + w0 + 4*wq;
    float4 re = *(const float4*)(yre + tbase + gi);
    float4 im = *(const float4*)(yim + tbase + gi);
    float4 mm = *(const float4*)(mask + mbase + gi);
    int off = offmap(h);
    const float SC = 1.0f/384.0f;
    dbuf[(4*wq  )*CPITCH + off] = make_float2(re.x*mm.x*SC, im.x*mm.x*SC);
    dbuf[(4*wq+1)*CPITCH + off] = make_float2(re.y*mm.y*SC, im.y*mm.y*SC);
    dbuf[(4*wq+2)*CPITCH + off] = make_float2(re.z*mm.z*SC, im.z*mm.z*SC);
    dbuf[(4*wq+3)*CPITCH + off] = make_float2(re.w*mm.w*SC, im.w*mm.w*SC);
  }
  __syncthreads();

  float2* drow = dbuf + col*CPITCH;
  int m = rev5(li);
  float2 v[12];
#pragma unroll
  for (int k = 0; k < 12; ++k) v[k] = drow[offmap(32*k + li)];
  fft384<1>(v, li);
  wave_fence();
#pragma unroll
  for (int k = 0; k < 12; ++k) drow[13*m + k] = v[k];
  __syncthreads();

#pragma unroll
  for (int t = 0; t < 6; ++t) {
    int pi = tid + CTPB*t;
    int h = pi / 6, wp = pi - 6*h;
    int off = offmap(h);
    float2 a = dbuf[(2*wp  )*CPITCH + off];
    float2 bq = dbuf[(2*wp+1)*CPITCH + off];
    *(float4*)(tmp + tbase + (size_t)h*Wn + w0 + 2*wp) = make_float4(a.x, a.y, bq.x, bq.y);
  }
}

// ---------------- CG scalar/vector kernels (float4 = 2 complex) ----------------

#define NPIX2 (NPIX/2)

__device__ __forceinline__ void block_reduce_atomic(float sum, float* target)
{
  __shared__ float red[TPB];
  red[threadIdx.x] = sum; __syncthreads();
  for (int s = TPB/2; s > 0; s >>= 1) {
    if (threadIdx.x < s) red[threadIdx.x] += red[threadIdx.x + s];
    __syncthreads();
  }
  if (threadIdx.x == 0) unsafeAtomicAdd(target, red[0]);
}

template<int GRPt>
__global__ __launch_bounds__(TPB) void k_rhs_init(
    const float* __restrict__ xre, const float* __restrict__ xim,
    const float* __restrict__ lam, const float2* __restrict__ partial,
    float2* __restrict__ r, float2* __restrict__ p, float2* __restrict__ x,
    float* __restrict__ scal)
{
  int b = blockIdx.y;
  float l = lam[0];
  float sum = 0.0f;
  const float2* xr2 = (const float2*)(xre + (size_t)b*NPIX);
  const float2* xi2 = (const float2*)(xim + (size_t)b*NPIX);
  float4* r4 = (float4*)(r + (size_t)b*NPIX);
  float4* p4 = (float4*)(p + (size_t)b*NPIX);
  float4* x4 = (float4*)(x + (size_t)b*NPIX);
  for (int i = blockIdx.x*TPB + threadIdx.x; i < NPIX2; i += RED_BLKS*TPB) {
    float2 re = xr2[i], im = xi2[i];
    float4 rv = make_float4(l*re.x, l*im.x, l*re.y, l*im.y);
#pragma unroll
    for (int g = 0; g < GRPt; ++g) {
      float4 pv = ((const float4*)(partial + ((size_t)g*Bn + b)*NPIX))[i];
      rv.x += pv.x; rv.y += pv.y; rv.z += pv.z; rv.w += pv.w;
    }
    r4[i] = rv; p4[i] = rv;
    x4[i] = make_float4(0.f, 0.f, 0.f, 0.f);
    sum += rv.x*rv.x + rv.y*rv.y + rv.z*rv.z + rv.w*rv.w;
  }
  block_reduce_atomic(sum, &scal[b]);
}

template<int GRPt>
__global__ __launch_bounds__(TPB) void k_combine_dot(
    const float2* __restrict__ p, const float* __restrict__ lam,
    const float2* __restrict__ partial, float2* __restrict__ Ap,
    float* __restrict__ slot)
{
  int b = blockIdx.y;
  float l = lam[0];
  float sum = 0.0f;
  const float4* p4 = (const float4*)(p + (size_t)b*NPIX);
  float4* A4 = (float4*)(Ap + (size_t)b*NPIX);
  for (int i = blockIdx.x*TPB + threadIdx.x; i < NPIX2; i += RED_BLKS*TPB) {
    float4 pv = p4[i];
    float4 av = make_float4(l*pv.x, l*pv.y, l*pv.z, l*pv.w);
#pragma unroll
    for (int g = 0; g < GRPt; ++g) {
      float4 qv = ((const float4*)(partial + ((size_t)g*Bn + b)*NPIX))[i];
      av.x += qv.x; av.y += qv.y; av.z += qv.z; av.w += qv.w;
    }
    A4[i] = av;
    sum += pv.x*av.x + pv.y*av.y + pv.z*av.z + pv.w*av.w;
  }
  block_reduce_atomic(sum, &slot[b]);
}

__global__ __launch_bounds__(TPB) void k_upd1(
    float2* __restrict__ x, float2* __restrict__ r,
    const float2* __restrict__ p, const float2* __restrict__ Ap,
    const float* __restrict__ rtr_cur, float* __restrict__ rtr_new,
    const float* __restrict__ pap)
{
  int b = blockIdx.y;
  float rtr = rtr_cur[b];
  bool act = rtr > TOLF;
  float alpha = act ? rtr / pap[b] : 0.0f;
  float sum = 0.0f;
  float4* x4 = (float4*)(x + (size_t)b*NPIX);
  float4* r4 = (float4*)(r + (size_t)b*NPIX);
  const float4* p4 = (const float4*)(p + (size_t)b*NPIX);
  const float4* A4 = (const float4*)(Ap + (size_t)b*NPIX);
  for (int i = blockIdx.x*TPB + threadIdx.x; i < NPIX2; i += RED_BLKS*TPB) {
    float4 rv = r4[i];
    if (act) {
      float4 pv = p4[i], av = A4[i], xv = x4[i];
      xv.x += alpha*pv.x; xv.y += alpha*pv.y; xv.z += alpha*pv.z; xv.w += alpha*pv.w;
      rv.x -= alpha*av.x; rv.y -= alpha*av.y; rv.z -= alpha*av.z; rv.w -= alpha*av.w;
      x4[i] = xv; r4[i] = rv;
    }
    sum += rv.x*rv.x + rv.y*rv.y + rv.z*rv.z + rv.w*rv.w;
  }
  block_reduce_atomic(sum, &rtr_new[b]);
}

__global__ __launch_bounds__(TPB) void k_upd2(
    float2* __restrict__ p, const float2* __restrict__ r,
    const float* __restrict__ rtr_cur, const float* __restrict__ rtr_new)
{
  int b = blockIdx.y;
  float rtr = rtr_cur[b];
  if (!(rtr > TOLF)) return;
  float beta = rtr_new[b] / rtr;
  float4* p4 = (float4*)(p + (size_t)b*NPIX);
  const float4* r4 = (const float4*)(r + (size_t)b*NPIX);
  for (int i = blockIdx.x*TPB + threadIdx.x; i < NPIX2; i += RED_BLKS*TPB) {
    float4 rv = r4[i];
    float4 pv = p4[i];
    p4[i] = make_float4(rv.x + beta*pv.x, rv.y + beta*pv.y,
                        rv.z + beta*pv.z, rv.w + beta*pv.w);
  }
}

// ---------------- launch ----------------

extern "C" void kernel_launch(void* const* d_in, const int* in_sizes, int n_in,
                              void* d_out, int out_size, void* d_ws, size_t ws_size,
                              hipStream_t stream)
{
  const float* lam  = (const float*)d_in[0];
  const float* xre  = (const float*)d_in[1];
  const float* xim  = (const float*)d_in[2];
  const float* yre  = (const float*)d_in[3];
  const float* yim  = (const float*)d_in[4];
  const float* sre  = (const float*)d_in[5];
  const float* sim  = (const float*)d_in[6];
  const float* mask = (const float*)d_in[7];

  const size_t szTmp  = (size_t)Bn*Cn*NPIX*sizeof(float2);
  const size_t szVec  = (size_t)Bn*NPIX*sizeof(float2);
  const size_t szMask = (size_t)Bn*NPIX*sizeof(float);
  const size_t need8  = szTmp + 8*szVec + 3*szVec + 512 + szMask;
  const int GRP = (ws_size >= need8) ? 8 : 4;   // ws_size fixed -> same path every call

  char* ws = (char*)d_ws;
  float2* tmp  = (float2*)ws;  ws += szTmp;
  float2* part = (float2*)ws;  ws += (size_t)GRP*szVec;
  float2* r    = (float2*)ws;  ws += szVec;
  float2* p    = (float2*)ws;  ws += szVec;
  float2* Ap   = (float2*)ws;  ws += szVec;
  float*  scal = (float*)ws;   ws += 512;   // rTr[11][B] at [0..43], pAp[10][B] at [44..83]
  float*  mskP = (float*)ws;
  float2* x    = (float2*)d_out;

  dim3 blk(TPB);
  dim3 rg(RED_BLKS, Bn);
  int grid_row = Bn*Cn*(Hn/8);       // 3072
  int grid_col = Bn*Cn*(Wn/NCOL);    // 2048
  int grid_inv = Bn*GRP*(Hn/8);      // 1536 (GRP=8) / 768 (GRP=4)

  k_maskp<<<(Bn*NPIX)/TPB, blk, 0, stream>>>(mask, mskP, scal);

  // ---- rhs = AH(y) + lambda*x ----
  k_col_rhs<<<grid_col, CTPB, 0, stream>>>(yre, yim, mask, tmp);
  if (GRP == 8) {
    k_row_inv_acc<2><<<grid_inv, blk, 0, stream>>>(tmp, sre, sim, part);
    k_rhs_init<8><<<rg, blk, 0, stream>>>(xre, xim, lam, part, r, p, x, scal);
  } else {
    k_row_inv_acc<4><<<grid_inv, blk, 0, stream>>>(tmp, sre, sim, part);
    k_rhs_init<4><<<rg, blk, 0, stream>>>(xre, xim, lam, part, r, p, x, scal);
  }

  for (int it = 0; it < NITER; ++it) {
    k_row_fwd<<<grid_row, blk, 0, stream>>>(p, sre, sim, tmp);
    k_col_full<<<grid_col, CTPB, 0, stream>>>(tmp, mskP);
    if (GRP == 8) {
      k_row_inv_acc<2><<<grid_inv, blk, 0, stream>>>(tmp, sre, sim, part);
      k_combine_dot<8><<<rg, blk, 0, stream>>>(p, lam, part, Ap, scal + 44 + it*Bn);
    } else {
      k_row_inv_acc<4><<<grid_inv, blk, 0, stream>>>(tmp, sre, sim, part);
      k_combine_dot<4><<<rg, blk, 0, stream>>>(p, lam, part, Ap, scal + 44 + it*Bn);
    }
    k_upd1<<<rg, blk, 0, stream>>>(x, r, p, Ap, scal + it*Bn, scal + (it+1)*Bn, scal + 44 + it*Bn);
    if (it < NITER-1)
      k_upd2<<<rg, blk, 0, stream>>>(p, r, scal + it*Bn, scal + (it+1)*Bn);
  }
}

// Round 6
// 1579.879 us; speedup vs baseline: 1.1825x; 1.1825x over previous
//
#include <hip/hip_runtime.h>
#include <hip/hip_fp16.h>

// CG-SENSE: B=4, C=16, H=W=384. x lives in d_out (float2 == [.,2]).
// FFT-384 = wave-synchronous four-step: in-register FFT-12, per-lane twiddle,
// cross-lane FFT-32 via ds_swizzle. Unscramble via LDS, 13-stride layout:
// natural index w at LDS offset offmap(w) = w + w/12.
// tmp (k-space intermediate) stored as fp16 (__half2 per complex) - halves HBM.
// Col kernels: 16-col panels, 512 threads (3 blocks/CU - known-good R4 shape).
// CG tail: combine+3dots -> scalar kernel (CG identity for rTrNew) -> fused upd.

#define Bn 4
#define Cn 16
#define Hn 384
#define Wn 384
#define NPIX (Hn*Wn)
#define NPIX2 (NPIX/2)
#define TPB 256
#define CTPB 512
#define NCOL 16
#define TOLF 1e-10f
#define NITER 10
#define RED_BLKS 72
#define RPITCH 416   // row-kernel LDS pitch (float2)
#define CPITCH 417   // col-kernel pitch (float2): 834 words % 32 == 2

__device__ __forceinline__ float2 cadd(float2 a, float2 b){ return make_float2(a.x+b.x, a.y+b.y); }
__device__ __forceinline__ float2 csub(float2 a, float2 b){ return make_float2(a.x-b.x, a.y-b.y); }
__device__ __forceinline__ float2 cmulf(float2 a, float2 b){
  return make_float2(a.x*b.x - a.y*b.y, a.x*b.y + a.y*b.x);
}

// wave-local LDS fence: DS ops are in-order per wave; write->fence->read within
// a wave is safe without s_barrier.
__device__ __forceinline__ void wave_fence(){ asm volatile("s_waitcnt lgkmcnt(0)" ::: "memory"); }

template<int IMM>
__device__ __forceinline__ float2 shx(float2 v){
  int x = __builtin_amdgcn_ds_swizzle(__float_as_int(v.x), IMM);
  int y = __builtin_amdgcn_ds_swizzle(__float_as_int(v.y), IMM);
  return make_float2(__int_as_float(x), __int_as_float(y));
}

__device__ __forceinline__ int rev5(int x){
  return ((x&1)<<4) | ((x&2)<<2) | (x&4) | ((x&8)>>2) | ((x&16)>>4);
}

__device__ __forceinline__ int offmap(int w){ return w + ((w*683)>>13); }  // w + w/12, w<384

// ---- in-register FFT-12 (natural in, natural out). 12 = 3x4 ----
template<int DIR>
__device__ __forceinline__ void fft12(float2* v)
{
  const float S3 = (DIR<0) ? -0.86602540378443864676f : 0.86602540378443864676f;
  const float sg = (DIR<0) ? -1.f : 1.f;
  float2 t[4][3];
#pragma unroll
  for (int b = 0; b < 4; ++b) {
    float2 a0 = v[b], a1 = v[4+b], a2 = v[8+b];
    float2 s = cadd(a1,a2), d = csub(a1,a2);
    float2 mm = make_float2(a0.x - 0.5f*s.x, a0.y - 0.5f*s.y);
    float2 e  = make_float2(-d.y*S3, d.x*S3);
    t[b][0] = cadd(a0,s);
    t[b][1] = cadd(mm,e);
    t[b][2] = csub(mm,e);
  }
  const float2 w1  = make_float2(0.86602540378443864676f, sg*0.5f);
  const float2 w2  = make_float2(0.5f, sg*0.86602540378443864676f);
  const float2 w3  = make_float2(0.f, sg);
  const float2 w4t = make_float2(-0.5f, sg*0.86602540378443864676f);
  const float2 w6  = make_float2(-1.f, 0.f);
  t[1][1] = cmulf(t[1][1], w1);  t[1][2] = cmulf(t[1][2], w2);
  t[2][1] = cmulf(t[2][1], w2);  t[2][2] = cmulf(t[2][2], w4t);
  t[3][1] = cmulf(t[3][1], w3);  t[3][2] = cmulf(t[3][2], w6);
#pragma unroll
  for (int c = 0; c < 3; ++c) {
    float2 e = cadd(t[0][c], t[2][c]);
    float2 f = csub(t[0][c], t[2][c]);
    float2 g = cadd(t[1][c], t[3][c]);
    float2 h = csub(t[1][c], t[3][c]);
    float2 ih = (DIR<0) ? make_float2(h.y, -h.x) : make_float2(-h.y, h.x);
    v[c]   = cadd(e,g);
    v[c+3] = cadd(f,ih);
    v[c+6] = csub(e,g);
    v[c+9] = csub(f,ih);
  }
}

// ---- cross-lane FFT-32 over lanes (natural in, bit-reversed lane out) ----
template<int DIR>
__device__ __forceinline__ void fft32_lanes(float2* v, int li)
{
  const float c2pi = (DIR<0) ? -6.2831853071795864769f : 6.2831853071795864769f;
  const float sg   = (DIR<0) ? -1.f : 1.f;
  float s, c;
  __sincosf(c2pi*(1.f/32.f)*(float)(li&15), &s, &c); float2 wA = make_float2(c,s);
  __sincosf(c2pi*(1.f/16.f)*(float)(li&7),  &s, &c); float2 wB = make_float2(c,s);
  __sincosf(c2pi*(1.f/ 8.f)*(float)(li&3),  &s, &c); float2 wC = make_float2(c,s);
  bool bA = li & 16, bB = li & 8, bC = li & 4, bD = li & 2, bE = li & 1;
#pragma unroll
  for (int k = 0; k < 12; ++k) {
    float2 a = v[k], o;
    o = shx<0x401F>(a); a = bA ? cmulf(csub(o,a), wA) : cadd(a,o);
    o = shx<0x201F>(a); a = bB ? cmulf(csub(o,a), wB) : cadd(a,o);
    o = shx<0x101F>(a); a = bC ? cmulf(csub(o,a), wC) : cadd(a,o);
    o = shx<0x081F>(a);
    { float2 su = cadd(a,o), d = csub(o,a);
      float2 dw = bE ? make_float2(-sg*d.y, sg*d.x) : d;
      a = bD ? dw : su; }
    o = shx<0x041F>(a); a = bE ? csub(o,a) : cadd(a,o);
    v[k] = a;
  }
}

// Full 384-pt FFT. In: reg k = x[32k+li]. Out: reg k1 = X[k1 + 12*rev5(li)].
template<int DIR>
__device__ __forceinline__ void fft384(float2* v, int li)
{
  fft12<DIR>(v);
  const float c2pi = (DIR<0) ? -6.2831853071795864769f : 6.2831853071795864769f;
  float s, c;
  __sincosf(c2pi*(1.f/384.f)*(float)li, &s, &c);
  float2 W = make_float2(c,s), cw = W;
#pragma unroll
  for (int k = 1; k < 12; ++k) { v[k] = cmulf(v[k], cw); cw = cmulf(cw, W); }
  fft32_lanes<DIR>(v, li);
}

// ---------------- FFT kernels ----------------

// tmp[b,c,h,:] = FFT_w( S[b,c,h,:] * p[b,h,:] )   (unnormalized fwd, fp16 out)
__global__ __launch_bounds__(TPB) void k_row_fwd(
    const float2* __restrict__ p, const float* __restrict__ Sre,
    const float* __restrict__ Sim, __half2* __restrict__ tmp)
{
  __shared__ float2 lbuf[8*RPITCH];
  int tid = threadIdx.x;
  int wave = tid>>6, lane = tid&63, sub = lane>>5, li = lane&31;
  int row = wave*2 + sub;
  int tile = blockIdx.x % (Hn/8);
  int bc   = blockIdx.x / (Hn/8);
  int b = bc / Cn;
  int h = tile*8 + row;
  size_t gbase = (size_t)bc*NPIX + (size_t)h*Wn;
  size_t pbase = (size_t)b*NPIX + (size_t)h*Wn;

  float2 v[12];
#pragma unroll
  for (int k = 0; k < 12; ++k) {
    int w = 32*k + li;
    float2 pv = p[pbase + w];
    float sr = Sre[gbase + w], si = Sim[gbase + w];
    v[k] = make_float2(sr*pv.x - si*pv.y, sr*pv.y + si*pv.x);
  }
  fft384<-1>(v, li);
  int m = rev5(li);
  float2* lrow = lbuf + row*RPITCH;
#pragma unroll
  for (int k = 0; k < 12; ++k) lrow[13*m + k] = v[k];
  wave_fence();
#pragma unroll
  for (int k = 0; k < 12; ++k) {
    int w = 32*k + li;
    tmp[gbase + w] = __float22half2_rn(lrow[offmap(w)]);
  }
}

// partial[g,b] = sum_{c in group g} conj(S[b,c]) * IFFT_w(tmp[b,c])
// Software-pipelined: next coil's fp16 loads stay in flight during current FFT.
template<int CPGt>
__global__ __launch_bounds__(TPB) void k_row_inv_acc(
    const __half2* __restrict__ tmp, const float* __restrict__ Sre,
    const float* __restrict__ Sim, float2* __restrict__ partial)
{
  const int GRPt = Cn/CPGt;
  __shared__ float2 lbuf[8*RPITCH];
  int tid = threadIdx.x;
  int wave = tid>>6, lane = tid&63, sub = lane>>5, li = lane&31;
  int row = wave*2 + sub;
  int tile = blockIdx.x % (Hn/8);
  int rest = blockIdx.x / (Hn/8);
  int g = rest % GRPt;
  int b = rest / GRPt;
  int h = tile*8 + row;
  int m = rev5(li);
  float2* lrow = lbuf + row*RPITCH;

  size_t gbase0 = ((size_t)b*Cn + g*CPGt)*NPIX + (size_t)h*Wn;
  __half2 hb[12];
#pragma unroll
  for (int k = 0; k < 12; ++k) hb[k] = tmp[gbase0 + 32*k + li];

  float2 acc[12];
#pragma unroll
  for (int k = 0; k < 12; ++k) acc[k] = make_float2(0.f, 0.f);

  for (int j = 0; j < CPGt; ++j) {
    size_t gb = gbase0 + (size_t)j*NPIX;
    float2 vc[12];
#pragma unroll
    for (int k = 0; k < 12; ++k) vc[k] = __half22float2(hb[k]);
    if (j + 1 < CPGt) {               // issue next coil's loads before any fence
      size_t gbn = gb + NPIX;
#pragma unroll
      for (int k = 0; k < 12; ++k) hb[k] = tmp[gbn + 32*k + li];
    }
    fft384<1>(vc, li);
    wave_fence();                     // WAR: prior gather reads drained
#pragma unroll
    for (int k = 0; k < 12; ++k) lrow[13*m + k] = vc[k];
    wave_fence();                     // RAW: writes visible before gather
#pragma unroll
    for (int k = 0; k < 12; ++k) {
      int w = 32*k + li;
      float2 u = lrow[offmap(w)];
      float sr = Sre[gb + w], si = Sim[gb + w];
      acc[k].x += sr*u.x + si*u.y;
      acc[k].y += sr*u.y - si*u.x;
    }
  }
  size_t pbase = ((size_t)g*Bn + b)*NPIX + (size_t)h*Wn;
#pragma unroll
  for (int k = 0; k < 12; ++k) partial[pbase + 32*k + li] = acc[k];
}

// lane-permuted scaled mask + scal zeroing.
// maskP[((b*Wn+w)*32+li)*12+k] = mask[b][k+12*rev5(li)][w]/NPIX
__global__ __launch_bounds__(TPB) void k_maskp(
    const float* __restrict__ mask, float* __restrict__ maskP,
    float* __restrict__ scal)
{
  int idx = blockIdx.x*TPB + threadIdx.x;
  if (blockIdx.x == 0) scal[threadIdx.x] = 0.0f;
  if (idx >= Bn*NPIX) return;
  int k = idx % 12; int t = idx / 12;
  int li = t & 31; t >>= 5;
  int w = t % Wn;  int b = t / Wn;
  maskP[idx] = mask[((size_t)b*Hn + (k + 12*rev5(li)))*Wn + w] * (1.0f/(float)NPIX);
}

// column pass: fwd FFT_h, * maskP, inv FFT_h. 16 columns, 512 threads.
__global__ __launch_bounds__(CTPB) void k_col_full(
    __half2* __restrict__ tmp, const float* __restrict__ maskP)
{
  __shared__ float2 dbuf[NCOL*CPITCH];   // 53376 B -> 3 blocks/CU
  int tid = threadIdx.x;
  int wave = tid>>6, lane = tid&63, sub = lane>>5, li = lane&31;
  int col = wave*2 + sub;
  int tile = blockIdx.x % (Wn/NCOL);
  int bc   = blockIdx.x / (Wn/NCOL);
  int b = bc / Cn;
  int w0 = tile*NCOL;
  size_t tbase = (size_t)bc*NPIX;

  for (int e = tid; e < NCOL*Hn; e += CTPB) {
    int wi = e & (NCOL-1), h = e >> 4;
    dbuf[wi*CPITCH + offmap(h)] = __half22float2(tmp[tbase + (size_t)h*Wn + w0 + wi]);
  }
  __syncthreads();

  float2* drow = dbuf + col*CPITCH;
  int w = w0 + col;
  int m = rev5(li);
  const float4* mp4 = (const float4*)(maskP + (((size_t)b*Wn + w)*32 + li)*12);
  float4 m0 = mp4[0], m1 = mp4[1], m2 = mp4[2];
  float2 v[12];
#pragma unroll
  for (int k = 0; k < 12; ++k) v[k] = drow[offmap(32*k + li)];
  fft384<-1>(v, li);
  float mk[12] = {m0.x,m0.y,m0.z,m0.w, m1.x,m1.y,m1.z,m1.w, m2.x,m2.y,m2.z,m2.w};
#pragma unroll
  for (int k = 0; k < 12; ++k) v[k] = make_float2(v[k].x*mk[k], v[k].y*mk[k]);
  wave_fence();
#pragma unroll
  for (int k = 0; k < 12; ++k) drow[13*m + k] = v[k];    // unscramble store
  wave_fence();
#pragma unroll
  for (int k = 0; k < 12; ++k) v[k] = drow[offmap(32*k + li)];  // natural reload
  fft384<1>(v, li);
  wave_fence();
#pragma unroll
  for (int k = 0; k < 12; ++k) drow[13*m + k] = v[k];
  __syncthreads();

  for (int e = tid; e < NCOL*Hn; e += CTPB) {
    int wi = e & (NCOL-1), h = e >> 4;
    tmp[tbase + (size_t)h*Wn + w0 + wi] = __float22half2_rn(dbuf[wi*CPITCH + offmap(h)]);
  }
}

// rhs column pass: stage y*mask*(1/384), inverse column FFT only.
__global__ __launch_bounds__(CTPB) void k_col_rhs(
    const float* __restrict__ yre, const float* __restrict__ yim,
    const float* __restrict__ mask, __half2* __restrict__ tmp)
{
  __shared__ float2 dbuf[NCOL*CPITCH];
  int tid = threadIdx.x;
  int wave = tid>>6, lane = tid&63, sub = lane>>5, li = lane&31;
  int col = wave*2 + sub;
  int tile = blockIdx.x % (Wn/NCOL);
  int bc   = blockIdx.x / (Wn/NCOL);
  int b = bc / Cn;
  int w0 = tile*NCOL;
  size_t tbase = (size_t)bc*NPIX;
  size_t mbase = (size_t)b*NPIX;

  for (int e = tid; e < NCOL*Hn; e += CTPB) {
    int wi = e & (NCOL-1), h = e >> 4;
    size_t gi = (size_t)h*Wn + w0 + wi;
    float mv = mask[mbase + gi] * (1.0f/384.0f);
    dbuf[wi*CPITCH + offmap(h)] = make_float2(yre[tbase+gi]*mv, yim[tbase+gi]*mv);
  }
  __syncthreads();

  float2* drow = dbuf + col*CPITCH;
  int m = rev5(li);
  float2 v[12];
#pragma unroll
  for (int k = 0; k < 12; ++k) v[k] = drow[offmap(32*k + li)];
  fft384<1>(v, li);
  wave_fence();
#pragma unroll
  for (int k = 0; k < 12; ++k) drow[13*m + k] = v[k];
  __syncthreads();

  for (int e = tid; e < NCOL*Hn; e += CTPB) {
    int wi = e & (NCOL-1), h = e >> 4;
    tmp[tbase + (size_t)h*Wn + w0 + wi] = __float22half2_rn(dbuf[wi*CPITCH + offmap(h)]);
  }
}

// ---------------- CG tail (float4 = 2 complex) ----------------

__device__ __forceinline__ void block_reduce_atomic(float sum, float* target)
{
  __shared__ float red[TPB];
  red[threadIdx.x] = sum; __syncthreads();
  for (int s = TPB/2; s > 0; s >>= 1) {
    if (threadIdx.x < s) red[threadIdx.x] += red[threadIdx.x + s];
    __syncthreads();
  }
  if (threadIdx.x == 0) unsafeAtomicAdd(target, red[0]);
  __syncthreads();
}

template<int GRPt>
__global__ __launch_bounds__(TPB) void k_rhs_init(
    const float* __restrict__ xre, const float* __restrict__ xim,
    const float* __restrict__ lam, const float2* __restrict__ partial,
    float2* __restrict__ r, float2* __restrict__ p, float2* __restrict__ x,
    float* __restrict__ scal)
{
  int b = blockIdx.y;
  float l = lam[0];
  float sum = 0.0f;
  const float2* xr2 = (const float2*)(xre + (size_t)b*NPIX);
  const float2* xi2 = (const float2*)(xim + (size_t)b*NPIX);
  float4* r4 = (float4*)(r + (size_t)b*NPIX);
  float4* p4 = (float4*)(p + (size_t)b*NPIX);
  float4* x4 = (float4*)(x + (size_t)b*NPIX);
  for (int i = blockIdx.x*TPB + threadIdx.x; i < NPIX2; i += RED_BLKS*TPB) {
    float2 re = xr2[i], im = xi2[i];
    float4 rv = make_float4(l*re.x, l*im.x, l*re.y, l*im.y);
#pragma unroll
    for (int g = 0; g < GRPt; ++g) {
      float4 pv = ((const float4*)(partial + ((size_t)g*Bn + b)*NPIX))[i];
      rv.x += pv.x; rv.y += pv.y; rv.z += pv.z; rv.w += pv.w;
    }
    r4[i] = rv; p4[i] = rv;
    x4[i] = make_float4(0.f, 0.f, 0.f, 0.f);
    sum += rv.x*rv.x + rv.y*rv.y + rv.z*rv.z + rv.w*rv.w;
  }
  block_reduce_atomic(sum, &scal[b]);
}

// Ap = lambda*p + sum_g partial[g]; dots: pAp, ApAp, rAp -> slot[{0,4,8}+b]
template<int GRPt>
__global__ __launch_bounds__(TPB) void k_combine_dot3(
    const float2* __restrict__ p, const float2* __restrict__ r,
    const float* __restrict__ lam, const float2* __restrict__ partial,
    float2* __restrict__ Ap, float* __restrict__ slot)
{
  int b = blockIdx.y;
  float l = lam[0];
  float s_pAp = 0.f, s_AA = 0.f, s_rA = 0.f;
  const float4* p4 = (const float4*)(p + (size_t)b*NPIX);
  const float4* r4 = (const float4*)(r + (size_t)b*NPIX);
  float4* A4 = (float4*)(Ap + (size_t)b*NPIX);
  for (int i = blockIdx.x*TPB + threadIdx.x; i < NPIX2; i += RED_BLKS*TPB) {
    float4 pv = p4[i];
    float4 av = make_float4(l*pv.x, l*pv.y, l*pv.z, l*pv.w);
#pragma unroll
    for (int g = 0; g < GRPt; ++g) {
      float4 qv = ((const float4*)(partial + ((size_t)g*Bn + b)*NPIX))[i];
      av.x += qv.x; av.y += qv.y; av.z += qv.z; av.w += qv.w;
    }
    A4[i] = av;
    float4 rv = r4[i];
    s_pAp += pv.x*av.x + pv.y*av.y + pv.z*av.z + pv.w*av.w;
    s_AA  += av.x*av.x + av.y*av.y + av.z*av.z + av.w*av.w;
    s_rA  += rv.x*av.x + rv.y*av.y + rv.z*av.z + rv.w*av.w;
  }
  block_reduce_atomic(s_pAp, &slot[b]);
  block_reduce_atomic(s_AA,  &slot[4+b]);
  block_reduce_atomic(s_rA,  &slot[8+b]);
}

// alpha = rTr/pAp; rTrNew = rTr - 2a*rAp + a^2*ApAp; beta = rTrNew/rTr
__global__ void k_scal(float* __restrict__ scal, int it)
{
  int b = threadIdx.x;
  if (b >= Bn) return;
  float rtr = scal[it*4 + b];
  const float* slot = scal + 64 + it*12;
  float* ab = scal + 224 + it*12;
  bool act = rtr > TOLF;
  float alpha = act ? rtr / slot[b] : 0.f;
  float rtrn = act ? fmaxf(rtr - 2.f*alpha*slot[8+b] + alpha*alpha*slot[4+b], 0.f) : rtr;
  float beta = act ? rtrn / rtr : 0.f;
  scal[(it+1)*4 + b] = rtrn;
  ab[b] = alpha; ab[4+b] = beta; ab[8+b] = act ? 1.f : 0.f;
}

// x += alpha p; r -= alpha Ap; p = r + beta p   (skipped entirely if frozen)
__global__ __launch_bounds__(TPB) void k_upd(
    float2* __restrict__ x, float2* __restrict__ r, float2* __restrict__ p,
    const float2* __restrict__ Ap, const float* __restrict__ ab)
{
  int b = blockIdx.y;
  if (!(ab[8+b] > 0.5f)) return;
  float alpha = ab[b], beta = ab[4+b];
  float4* x4 = (float4*)(x + (size_t)b*NPIX);
  float4* r4 = (float4*)(r + (size_t)b*NPIX);
  float4* p4 = (float4*)(p + (size_t)b*NPIX);
  const float4* A4 = (const float4*)(Ap + (size_t)b*NPIX);
  for (int i = blockIdx.x*TPB + threadIdx.x; i < NPIX2; i += RED_BLKS*TPB) {
    float4 pv = p4[i], av = A4[i], xv = x4[i], rv = r4[i];
    xv.x += alpha*pv.x; xv.y += alpha*pv.y; xv.z += alpha*pv.z; xv.w += alpha*pv.w;
    rv.x -= alpha*av.x; rv.y -= alpha*av.y; rv.z -= alpha*av.z; rv.w -= alpha*av.w;
    x4[i] = xv; r4[i] = rv;
    p4[i] = make_float4(rv.x + beta*pv.x, rv.y + beta*pv.y,
                        rv.z + beta*pv.z, rv.w + beta*pv.w);
  }
}

// ---------------- launch ----------------

extern "C" void kernel_launch(void* const* d_in, const int* in_sizes, int n_in,
                              void* d_out, int out_size, void* d_ws, size_t ws_size,
                              hipStream_t stream)
{
  const float* lam  = (const float*)d_in[0];
  const float* xre  = (const float*)d_in[1];
  const float* xim  = (const float*)d_in[2];
  const float* yre  = (const float*)d_in[3];
  const float* yim  = (const float*)d_in[4];
  const float* sre  = (const float*)d_in[5];
  const float* sim  = (const float*)d_in[6];
  const float* mask = (const float*)d_in[7];

  const size_t szTmp  = (size_t)Bn*Cn*NPIX*sizeof(__half2);   // 37.7 MB
  const size_t szVec  = (size_t)Bn*NPIX*sizeof(float2);       // 4.7 MB
  const size_t szMask = (size_t)Bn*NPIX*sizeof(float);        // 2.4 MB
  const size_t need8  = szTmp + 8*szVec + 3*szVec + 2048 + szMask;
  const int GRP = (ws_size >= need8) ? 8 : 4;   // ws_size fixed -> same path every call

  char* ws = (char*)d_ws;
  __half2* tmp = (__half2*)ws;  ws += szTmp;
  float2* part = (float2*)ws;   ws += (size_t)GRP*szVec;
  float2* r    = (float2*)ws;   ws += szVec;
  float2* p    = (float2*)ws;   ws += szVec;
  float2* Ap   = (float2*)ws;   ws += szVec;
  float*  scal = (float*)ws;    ws += 2048;
  // scal: rTr[11][4] @0..43 | dots[10][12] @64.. | alpha/beta/act[10][12] @224..
  float*  mskP = (float*)ws;
  float2* x    = (float2*)d_out;

  dim3 blk(TPB);
  dim3 rg(RED_BLKS, Bn);
  int grid_row = Bn*Cn*(Hn/8);       // 3072
  int grid_col = Bn*Cn*(Wn/NCOL);    // 1536
  int grid_inv = Bn*GRP*(Hn/8);      // 1536 (GRP=8) / 768 (GRP=4)

  k_maskp<<<(Bn*NPIX)/TPB, blk, 0, stream>>>(mask, mskP, scal);

  // ---- rhs = AH(y) + lambda*x ----
  k_col_rhs<<<grid_col, CTPB, 0, stream>>>(yre, yim, mask, tmp);
  if (GRP == 8) {
    k_row_inv_acc<2><<<grid_inv, blk, 0, stream>>>(tmp, sre, sim, part);
    k_rhs_init<8><<<rg, blk, 0, stream>>>(xre, xim, lam, part, r, p, x, scal);
  } else {
    k_row_inv_acc<4><<<grid_inv, blk, 0, stream>>>(tmp, sre, sim, part);
    k_rhs_init<4><<<rg, blk, 0, stream>>>(xre, xim, lam, part, r, p, x, scal);
  }

  for (int it = 0; it < NITER; ++it) {
    k_row_fwd<<<grid_row, blk, 0, stream>>>(p, sre, sim, tmp);
    k_col_full<<<grid_col, CTPB, 0, stream>>>(tmp, mskP);
    if (GRP == 8) {
      k_row_inv_acc<2><<<grid_inv, blk, 0, stream>>>(tmp, sre, sim, part);
      k_combine_dot3<8><<<rg, blk, 0, stream>>>(p, r, lam, part, Ap, scal + 64 + it*12);
    } else {
      k_row_inv_acc<4><<<grid_inv, blk, 0, stream>>>(tmp, sre, sim, part);
      k_combine_dot3<4><<<rg, blk, 0, stream>>>(p, r, lam, part, Ap, scal + 64 + it*12);
    }
    k_scal<<<1, 64, 0, stream>>>(scal, it);
    k_upd<<<rg, blk, 0, stream>>>(x, r, p, Ap, scal + 224 + it*12);
  }
}

// Round 7
// 1470.087 us; speedup vs baseline: 1.2708x; 1.0747x over previous
//
#include <hip/hip_runtime.h>
#include <hip/hip_fp16.h>

// CG-SENSE: B=4, C=16, H=W=384. x lives in d_out (float2 == [.,2]).
// FFT-384 four-step, wave-synchronous. Forward (DIF): fft12 -> twiddle ->
// fft32 across lanes; output reg k = X[k + 12*rev5(li)] (scrambled).
// Inverse (DIT, fft384_scr): consumes that scrambled register layout directly
// (transposed network: pre-twiddle + xor-exchange, stages reversed), outputs
// natural reg k = x[32k+li]. So:
//  - k_row_fwd: FFT + direct scrambled-w global store. NO LDS.
//  - k_row_inv_scr: scrambled load -> DIT inverse -> conj(S) acc. NO LDS.
//  - k_col_full: DIF fwd -> mask -> DIT inv in registers; LDS only for the
//    stage-in/out column transpose. maskP has the w-scramble folded in.
// tmp fp16 (__half2/complex); smaps packed to fp16 when ws_size allows.

#define Bn 4
#define Cn 16
#define Hn 384
#define Wn 384
#define NPIX (Hn*Wn)
#define NPIX2 (NPIX/2)
#define TPB 256
#define CTPB 512
#define NCOL 16
#define TOLF 1e-10f
#define NITER 10
#define RED_BLKS 72
#define GRP 4
#define CPG 4
#define RPITCH 416
#define CPITCH 417   // 834 words % 32 == 2 -> conflict-light

__device__ __forceinline__ float2 cadd(float2 a, float2 b){ return make_float2(a.x+b.x, a.y+b.y); }
__device__ __forceinline__ float2 csub(float2 a, float2 b){ return make_float2(a.x-b.x, a.y-b.y); }
__device__ __forceinline__ float2 cmulf(float2 a, float2 b){
  return make_float2(a.x*b.x - a.y*b.y, a.x*b.y + a.y*b.x);
}

__device__ __forceinline__ void wave_fence(){ asm volatile("s_waitcnt lgkmcnt(0)" ::: "memory"); }

template<int IMM>
__device__ __forceinline__ float2 shx(float2 v){
  int x = __builtin_amdgcn_ds_swizzle(__float_as_int(v.x), IMM);
  int y = __builtin_amdgcn_ds_swizzle(__float_as_int(v.y), IMM);
  return make_float2(__int_as_float(x), __int_as_float(y));
}

__device__ __forceinline__ int rev5(int x){
  return ((x&1)<<4) | ((x&2)<<2) | (x&4) | ((x&8)>>2) | ((x&16)>>4);
}

__device__ __forceinline__ int offmap(int w){ return w + ((w*683)>>13); }  // w + w/12, w<384

// ---- in-register FFT-12 (natural in, natural out), kernel w12^(DIR*j*k) ----
template<int DIR>
__device__ __forceinline__ void fft12(float2* v)
{
  const float S3 = (DIR<0) ? -0.86602540378443864676f : 0.86602540378443864676f;
  const float sg = (DIR<0) ? -1.f : 1.f;
  float2 t[4][3];
#pragma unroll
  for (int b = 0; b < 4; ++b) {
    float2 a0 = v[b], a1 = v[4+b], a2 = v[8+b];
    float2 s = cadd(a1,a2), d = csub(a1,a2);
    float2 mm = make_float2(a0.x - 0.5f*s.x, a0.y - 0.5f*s.y);
    float2 e  = make_float2(-d.y*S3, d.x*S3);
    t[b][0] = cadd(a0,s);
    t[b][1] = cadd(mm,e);
    t[b][2] = csub(mm,e);
  }
  const float2 w1  = make_float2(0.86602540378443864676f, sg*0.5f);
  const float2 w2  = make_float2(0.5f, sg*0.86602540378443864676f);
  const float2 w3  = make_float2(0.f, sg);
  const float2 w4t = make_float2(-0.5f, sg*0.86602540378443864676f);
  const float2 w6  = make_float2(-1.f, 0.f);
  t[1][1] = cmulf(t[1][1], w1);  t[1][2] = cmulf(t[1][2], w2);
  t[2][1] = cmulf(t[2][1], w2);  t[2][2] = cmulf(t[2][2], w4t);
  t[3][1] = cmulf(t[3][1], w3);  t[3][2] = cmulf(t[3][2], w6);
#pragma unroll
  for (int c = 0; c < 3; ++c) {
    float2 e = cadd(t[0][c], t[2][c]);
    float2 f = csub(t[0][c], t[2][c]);
    float2 g = cadd(t[1][c], t[3][c]);
    float2 h = csub(t[1][c], t[3][c]);
    float2 ih = (DIR<0) ? make_float2(h.y, -h.x) : make_float2(-h.y, h.x);
    v[c]   = cadd(e,g);
    v[c+3] = cadd(f,ih);
    v[c+6] = csub(e,g);
    v[c+9] = csub(f,ih);
  }
}

// ---- DIF FFT-32 across lanes: natural lane in, bit-reversed lane out ----
template<int DIR>
__device__ __forceinline__ void fft32_lanes(float2* v, int li)
{
  const float c2pi = (DIR<0) ? -6.2831853071795864769f : 6.2831853071795864769f;
  const float sg   = (DIR<0) ? -1.f : 1.f;
  float s, c;
  __sincosf(c2pi*(1.f/32.f)*(float)(li&15), &s, &c); float2 wA = make_float2(c,s);
  __sincosf(c2pi*(1.f/16.f)*(float)(li&7),  &s, &c); float2 wB = make_float2(c,s);
  __sincosf(c2pi*(1.f/ 8.f)*(float)(li&3),  &s, &c); float2 wC = make_float2(c,s);
  bool bA = li & 16, bB = li & 8, bC = li & 4, bD = li & 2, bE = li & 1;
#pragma unroll
  for (int k = 0; k < 12; ++k) {
    float2 a = v[k], o;
    o = shx<0x401F>(a); a = bA ? cmulf(csub(o,a), wA) : cadd(a,o);
    o = shx<0x201F>(a); a = bB ? cmulf(csub(o,a), wB) : cadd(a,o);
    o = shx<0x101F>(a); a = bC ? cmulf(csub(o,a), wC) : cadd(a,o);
    o = shx<0x081F>(a);
    { float2 su = cadd(a,o), d = csub(o,a);
      float2 dw = bE ? make_float2(-sg*d.y, sg*d.x) : d;
      a = bD ? dw : su; }
    o = shx<0x041F>(a); a = bE ? csub(o,a) : cadd(a,o);
    v[k] = a;
  }
}

// ---- DIT FFT-32 across lanes: bit-reversed lane in, natural lane out ----
// Transposed network of fft32_lanes: stages reversed, pre-twiddle on hi lanes.
template<int DIR>
__device__ __forceinline__ void fft32_lanes_dit(float2* v, int li)
{
  const float c2pi = (DIR<0) ? -6.2831853071795864769f : 6.2831853071795864769f;
  const float sg   = (DIR<0) ? -1.f : 1.f;
  float s, c;
  __sincosf(c2pi*(1.f/32.f)*(float)(li&15), &s, &c); float2 wA = make_float2(c,s);
  __sincosf(c2pi*(1.f/16.f)*(float)(li&7),  &s, &c); float2 wB = make_float2(c,s);
  __sincosf(c2pi*(1.f/ 8.f)*(float)(li&3),  &s, &c); float2 wC = make_float2(c,s);
  bool bA = li & 16, bB = li & 8, bC = li & 4, bD = li & 2, bE = li & 1;
#pragma unroll
  for (int k = 0; k < 12; ++k) {
    float2 a = v[k], o;
    // E' (xor1), no twiddle
    o = shx<0x041F>(a); a = bE ? csub(o,a) : cadd(a,o);
    // D' (xor2), pre-twiddle w4^(li&1) on hi lanes
    { float2 aw = make_float2(-sg*a.y, sg*a.x);      // i*a (sg=+1)
      a = (bD && bE) ? aw : a;
      o = shx<0x081F>(a); a = bD ? csub(o,a) : cadd(a,o); }
    // C' (xor4)
    { float2 aw = cmulf(a, wC); a = bC ? aw : a;
      o = shx<0x101F>(a); a = bC ? csub(o,a) : cadd(a,o); }
    // B' (xor8)
    { float2 aw = cmulf(a, wB); a = bB ? aw : a;
      o = shx<0x201F>(a); a = bB ? csub(o,a) : cadd(a,o); }
    // A' (xor16)
    { float2 aw = cmulf(a, wA); a = bA ? aw : a;
      o = shx<0x401F>(a); a = bA ? csub(o,a) : cadd(a,o); }
    v[k] = a;
  }
}

// Forward: in reg k = x[32k+li]. Out reg k1 = X[k1 + 12*rev5(li)].
template<int DIR>
__device__ __forceinline__ void fft384(float2* v, int li)
{
  fft12<DIR>(v);
  const float c2pi = (DIR<0) ? -6.2831853071795864769f : 6.2831853071795864769f;
  float s, c;
  __sincosf(c2pi*(1.f/384.f)*(float)li, &s, &c);
  float2 W = make_float2(c,s), cw = W;
#pragma unroll
  for (int k = 1; k < 12; ++k) { v[k] = cmulf(v[k], cw); cw = cmulf(cw, W); }
  fft32_lanes<DIR>(v, li);
}

// Scrambled-input transform: in reg k = X[k + 12*rev5(li)]. Out reg k = x[32k+li].
template<int DIR>
__device__ __forceinline__ void fft384_scr(float2* v, int li)
{
  fft32_lanes_dit<DIR>(v, li);
  const float c2pi = (DIR<0) ? -6.2831853071795864769f : 6.2831853071795864769f;
  float s, c;
  __sincosf(c2pi*(1.f/384.f)*(float)li, &s, &c);
  float2 W = make_float2(c,s), cw = W;
#pragma unroll
  for (int k = 1; k < 12; ++k) { v[k] = cmulf(v[k], cw); cw = cmulf(cw, W); }
  fft12<DIR>(v);
}

// ---------------- FFT kernels ----------------

// tmp[b,c,h,wa] = scrambled-w FFT_w(S*p). NO LDS.
template<bool HS>
__global__ __launch_bounds__(TPB) void k_row_fwd(
    const float2* __restrict__ p, const float* __restrict__ Sre,
    const float* __restrict__ Sim, const __half2* __restrict__ Sh,
    __half2* __restrict__ tmp)
{
  int tid = threadIdx.x;
  int wave = tid>>6, lane = tid&63, sub = lane>>5, li = lane&31;
  int row = wave*2 + sub;
  int tile = blockIdx.x % (Hn/8);
  int bc   = blockIdx.x / (Hn/8);
  int b = bc / Cn;
  int h = tile*8 + row;
  size_t gbase = (size_t)bc*NPIX + (size_t)h*Wn;
  size_t pbase = (size_t)b*NPIX + (size_t)h*Wn;

  float2 v[12];
#pragma unroll
  for (int k = 0; k < 12; ++k) {
    int w = 32*k + li;
    float2 pv = p[pbase + w];
    float sr, si;
    if (HS) { float2 sv = __half22float2(Sh[gbase + w]); sr = sv.x; si = sv.y; }
    else    { sr = Sre[gbase + w]; si = Sim[gbase + w]; }
    v[k] = make_float2(sr*pv.x - si*pv.y, sr*pv.y + si*pv.x);
  }
  fft384<-1>(v, li);
#pragma unroll
  for (int k = 0; k < 12; ++k)
    tmp[gbase + 32*k + li] = __float22half2_rn(v[k]);
}

// Iteration path: scrambled tmp -> DIT inverse -> conj(S) acc. NO LDS.
template<bool HS>
__global__ __launch_bounds__(TPB) void k_row_inv_scr(
    const __half2* __restrict__ tmp, const float* __restrict__ Sre,
    const float* __restrict__ Sim, const __half2* __restrict__ Sh,
    float2* __restrict__ partial)
{
  int tid = threadIdx.x;
  int wave = tid>>6, lane = tid&63, sub = lane>>5, li = lane&31;
  int row = wave*2 + sub;
  int tile = blockIdx.x % (Hn/8);
  int rest = blockIdx.x / (Hn/8);
  int g = rest % GRP;
  int b = rest / GRP;
  int h = tile*8 + row;

  size_t gbase0 = ((size_t)b*Cn + g*CPG)*NPIX + (size_t)h*Wn;
  __half2 hb[12];
#pragma unroll
  for (int k = 0; k < 12; ++k) hb[k] = tmp[gbase0 + 32*k + li];

  float2 acc[12];
#pragma unroll
  for (int k = 0; k < 12; ++k) acc[k] = make_float2(0.f, 0.f);

  for (int j = 0; j < CPG; ++j) {
    size_t gb = gbase0 + (size_t)j*NPIX;
    float2 vc[12];
#pragma unroll
    for (int k = 0; k < 12; ++k) vc[k] = __half22float2(hb[k]);
    if (j + 1 < CPG) {
      size_t gbn = gb + NPIX;
#pragma unroll
      for (int k = 0; k < 12; ++k) hb[k] = tmp[gbn + 32*k + li];
    }
    fft384_scr<1>(vc, li);            // natural-w registers
#pragma unroll
    for (int k = 0; k < 12; ++k) {
      int w = 32*k + li;
      float sr, si;
      if (HS) { float2 sv = __half22float2(Sh[gb + w]); sr = sv.x; si = sv.y; }
      else    { sr = Sre[gb + w]; si = Sim[gb + w]; }
      acc[k].x += sr*vc[k].x + si*vc[k].y;
      acc[k].y += sr*vc[k].y - si*vc[k].x;
    }
  }
  size_t pbase = ((size_t)g*Bn + b)*NPIX + (size_t)h*Wn;
#pragma unroll
  for (int k = 0; k < 12; ++k) partial[pbase + 32*k + li] = acc[k];
}

// rhs path (natural tmp from k_col_rhs), runs once: old LDS-unscramble variant.
__global__ __launch_bounds__(TPB) void k_row_inv_nat(
    const __half2* __restrict__ tmp, const float* __restrict__ Sre,
    const float* __restrict__ Sim, float2* __restrict__ partial)
{
  __shared__ float2 lbuf[8*RPITCH];
  int tid = threadIdx.x;
  int wave = tid>>6, lane = tid&63, sub = lane>>5, li = lane&31;
  int row = wave*2 + sub;
  int tile = blockIdx.x % (Hn/8);
  int rest = blockIdx.x / (Hn/8);
  int g = rest % GRP;
  int b = rest / GRP;
  int h = tile*8 + row;
  int m = rev5(li);
  float2* lrow = lbuf + row*RPITCH;

  size_t gbase0 = ((size_t)b*Cn + g*CPG)*NPIX + (size_t)h*Wn;
  __half2 hb[12];
#pragma unroll
  for (int k = 0; k < 12; ++k) hb[k] = tmp[gbase0 + 32*k + li];

  float2 acc[12];
#pragma unroll
  for (int k = 0; k < 12; ++k) acc[k] = make_float2(0.f, 0.f);

  for (int j = 0; j < CPG; ++j) {
    size_t gb = gbase0 + (size_t)j*NPIX;
    float2 vc[12];
#pragma unroll
    for (int k = 0; k < 12; ++k) vc[k] = __half22float2(hb[k]);
    if (j + 1 < CPG) {
      size_t gbn = gb + NPIX;
#pragma unroll
      for (int k = 0; k < 12; ++k) hb[k] = tmp[gbn + 32*k + li];
    }
    fft384<1>(vc, li);
    wave_fence();
#pragma unroll
    for (int k = 0; k < 12; ++k) lrow[13*m + k] = vc[k];
    wave_fence();
#pragma unroll
    for (int k = 0; k < 12; ++k) {
      int w = 32*k + li;
      float2 u = lrow[offmap(w)];
      float sr = Sre[gb + w], si = Sim[gb + w];
      acc[k].x += sr*u.x + si*u.y;
      acc[k].y += sr*u.y - si*u.x;
    }
  }
  size_t pbase = ((size_t)g*Bn + b)*NPIX + (size_t)h*Wn;
#pragma unroll
  for (int k = 0; k < 12; ++k) partial[pbase + 32*k + li] = acc[k];
}

// smaps -> packed fp16
__global__ __launch_bounds__(TPB) void k_spack(
    const float* __restrict__ sre, const float* __restrict__ sim,
    __half2* __restrict__ sh)
{
  size_t i = (size_t)blockIdx.x*TPB + threadIdx.x;
  if (i < (size_t)Bn*Cn*NPIX) sh[i] = __floats2half2_rn(sre[i], sim[i]);
}

// lane- and w-scramble-permuted scaled mask + scal zeroing.
// maskP[((b*Wn+wa)*32+li)*12+k] = mask[b][k+12*rev5(li)][wtrue(wa)]/NPIX
// wa = 32*q+s  ->  wtrue = q + 12*rev5(s)
__global__ __launch_bounds__(TPB) void k_maskp(
    const float* __restrict__ mask, float* __restrict__ maskP,
    float* __restrict__ scal)
{
  int idx = blockIdx.x*TPB + threadIdx.x;
  if (blockIdx.x == 0) scal[threadIdx.x] = 0.0f;
  if (idx >= Bn*NPIX) return;
  int k = idx % 12; int t = idx / 12;
  int li = t & 31; t >>= 5;
  int wa = t % Wn; int b = t / Wn;
  int wt = (wa >> 5) + 12*rev5(wa & 31);
  maskP[idx] = mask[((size_t)b*Hn + (k + 12*rev5(li)))*Wn + wt] * (1.0f/(float)NPIX);
}

// column pass: DIF fwd along h -> mask -> DIT inv, all in registers.
__global__ __launch_bounds__(CTPB) void k_col_full(
    __half2* __restrict__ tmp, const float* __restrict__ maskP)
{
  __shared__ float2 dbuf[NCOL*CPITCH];
  int tid = threadIdx.x;
  int wave = tid>>6, lane = tid&63, sub = lane>>5, li = lane&31;
  int col = wave*2 + sub;
  int tile = blockIdx.x % (Wn/NCOL);
  int bc   = blockIdx.x / (Wn/NCOL);
  int b = bc / Cn;
  int w0 = tile*NCOL;
  size_t tbase = (size_t)bc*NPIX;

  for (int e = tid; e < NCOL*Hn; e += CTPB) {
    int wi = e & (NCOL-1), h = e >> 4;
    dbuf[wi*CPITCH + offmap(h)] = __half22float2(tmp[tbase + (size_t)h*Wn + w0 + wi]);
  }
  __syncthreads();

  float2* drow = dbuf + col*CPITCH;
  int w = w0 + col;
  const float4* mp4 = (const float4*)(maskP + (((size_t)b*Wn + w)*32 + li)*12);
  float4 m0 = mp4[0], m1 = mp4[1], m2 = mp4[2];
  float2 v[12];
#pragma unroll
  for (int k = 0; k < 12; ++k) v[k] = drow[offmap(32*k + li)];
  fft384<-1>(v, li);                       // scrambled-h regs
  float mk[12] = {m0.x,m0.y,m0.z,m0.w, m1.x,m1.y,m1.z,m1.w, m2.x,m2.y,m2.z,m2.w};
#pragma unroll
  for (int k = 0; k < 12; ++k) v[k] = make_float2(v[k].x*mk[k], v[k].y*mk[k]);
  fft384_scr<1>(v, li);                    // natural-h regs
#pragma unroll
  for (int k = 0; k < 12; ++k) drow[offmap(32*k + li)] = v[k];  // own column, in-order DS
  __syncthreads();

  for (int e = tid; e < NCOL*Hn; e += CTPB) {
    int wi = e & (NCOL-1), h = e >> 4;
    tmp[tbase + (size_t)h*Wn + w0 + wi] = __float22half2_rn(dbuf[wi*CPITCH + offmap(h)]);
  }
}

// rhs column pass: stage y*mask*(1/384), inverse column FFT; natural tmp out.
__global__ __launch_bounds__(CTPB) void k_col_rhs(
    const float* __restrict__ yre, const float* __restrict__ yim,
    const float* __restrict__ mask, __half2* __restrict__ tmp)
{
  __shared__ float2 dbuf[NCOL*CPITCH];
  int tid = threadIdx.x;
  int wave = tid>>6, lane = tid&63, sub = lane>>5, li = lane&31;
  int col = wave*2 + sub;
  int tile = blockIdx.x % (Wn/NCOL);
  int bc   = blockIdx.x / (Wn/NCOL);
  int b = bc / Cn;
  int w0 = tile*NCOL;
  size_t tbase = (size_t)bc*NPIX;
  size_t mbase = (size_t)b*NPIX;

  for (int e = tid; e < NCOL*Hn; e += CTPB) {
    int wi = e & (NCOL-1), h = e >> 4;
    size_t gi = (size_t)h*Wn + w0 + wi;
    float mv = mask[mbase + gi] * (1.0f/384.0f);
    dbuf[wi*CPITCH + offmap(h)] = make_float2(yre[tbase+gi]*mv, yim[tbase+gi]*mv);
  }
  __syncthreads();

  float2* drow = dbuf + col*CPITCH;
  int m = rev5(li);
  float2 v[12];
#pragma unroll
  for (int k = 0; k < 12; ++k) v[k] = drow[offmap(32*k + li)];
  fft384<1>(v, li);
  wave_fence();
#pragma unroll
  for (int k = 0; k < 12; ++k) drow[13*m + k] = v[k];
  __syncthreads();

  for (int e = tid; e < NCOL*Hn; e += CTPB) {
    int wi = e & (NCOL-1), h = e >> 4;
    tmp[tbase + (size_t)h*Wn + w0 + wi] = __float22half2_rn(dbuf[wi*CPITCH + offmap(h)]);
  }
}

// ---------------- CG tail (float4 = 2 complex) ----------------

__device__ __forceinline__ void block_reduce_atomic(float sum, float* target)
{
  __shared__ float red[TPB];
  red[threadIdx.x] = sum; __syncthreads();
  for (int s = TPB/2; s > 0; s >>= 1) {
    if (threadIdx.x < s) red[threadIdx.x] += red[threadIdx.x + s];
    __syncthreads();
  }
  if (threadIdx.x == 0) unsafeAtomicAdd(target, red[0]);
  __syncthreads();
}

__global__ __launch_bounds__(TPB) void k_rhs_init(
    const float* __restrict__ xre, const float* __restrict__ xim,
    const float* __restrict__ lam, const float2* __restrict__ partial,
    float2* __restrict__ r, float2* __restrict__ p, float2* __restrict__ x,
    float* __restrict__ scal)
{
  int b = blockIdx.y;
  float l = lam[0];
  float sum = 0.0f;
  const float2* xr2 = (const float2*)(xre + (size_t)b*NPIX);
  const float2* xi2 = (const float2*)(xim + (size_t)b*NPIX);
  float4* r4 = (float4*)(r + (size_t)b*NPIX);
  float4* p4 = (float4*)(p + (size_t)b*NPIX);
  float4* x4 = (float4*)(x + (size_t)b*NPIX);
  for (int i = blockIdx.x*TPB + threadIdx.x; i < NPIX2; i += RED_BLKS*TPB) {
    float2 re = xr2[i], im = xi2[i];
    float4 rv = make_float4(l*re.x, l*im.x, l*re.y, l*im.y);
#pragma unroll
    for (int g = 0; g < GRP; ++g) {
      float4 pv = ((const float4*)(partial + ((size_t)g*Bn + b)*NPIX))[i];
      rv.x += pv.x; rv.y += pv.y; rv.z += pv.z; rv.w += pv.w;
    }
    r4[i] = rv; p4[i] = rv;
    x4[i] = make_float4(0.f, 0.f, 0.f, 0.f);
    sum += rv.x*rv.x + rv.y*rv.y + rv.z*rv.z + rv.w*rv.w;
  }
  block_reduce_atomic(sum, &scal[b]);
}

// Ap = lambda*p + sum_g partial[g]; dots pAp/ApAp/rAp -> slot[{0,4,8}+b]
__global__ __launch_bounds__(TPB) void k_combine_dot3(
    const float2* __restrict__ p, const float2* __restrict__ r,
    const float* __restrict__ lam, const float2* __restrict__ partial,
    float2* __restrict__ Ap, float* __restrict__ slot)
{
  int b = blockIdx.y;
  float l = lam[0];
  float s_pAp = 0.f, s_AA = 0.f, s_rA = 0.f;
  const float4* p4 = (const float4*)(p + (size_t)b*NPIX);
  const float4* r4 = (const float4*)(r + (size_t)b*NPIX);
  float4* A4 = (float4*)(Ap + (size_t)b*NPIX);
  for (int i = blockIdx.x*TPB + threadIdx.x; i < NPIX2; i += RED_BLKS*TPB) {
    float4 pv = p4[i];
    float4 av = make_float4(l*pv.x, l*pv.y, l*pv.z, l*pv.w);
#pragma unroll
    for (int g = 0; g < GRP; ++g) {
      float4 qv = ((const float4*)(partial + ((size_t)g*Bn + b)*NPIX))[i];
      av.x += qv.x; av.y += qv.y; av.z += qv.z; av.w += qv.w;
    }
    A4[i] = av;
    float4 rv = r4[i];
    s_pAp += pv.x*av.x + pv.y*av.y + pv.z*av.z + pv.w*av.w;
    s_AA  += av.x*av.x + av.y*av.y + av.z*av.z + av.w*av.w;
    s_rA  += rv.x*av.x + rv.y*av.y + rv.z*av.z + rv.w*av.w;
  }
  block_reduce_atomic(s_pAp, &slot[b]);
  block_reduce_atomic(s_AA,  &slot[4+b]);
  block_reduce_atomic(s_rA,  &slot[8+b]);
}

__global__ void k_scal(float* __restrict__ scal, int it)
{
  int b = threadIdx.x;
  if (b >= Bn) return;
  float rtr = scal[it*4 + b];
  const float* slot = scal + 64 + it*12;
  float* ab = scal + 224 + it*12;
  bool act = rtr > TOLF;
  float alpha = act ? rtr / slot[b] : 0.f;
  float rtrn = act ? fmaxf(rtr - 2.f*alpha*slot[8+b] + alpha*alpha*slot[4+b], 0.f) : rtr;
  float beta = act ? rtrn / rtr : 0.f;
  scal[(it+1)*4 + b] = rtrn;
  ab[b] = alpha; ab[4+b] = beta; ab[8+b] = act ? 1.f : 0.f;
}

__global__ __launch_bounds__(TPB) void k_upd(
    float2* __restrict__ x, float2* __restrict__ r, float2* __restrict__ p,
    const float2* __restrict__ Ap, const float* __restrict__ ab)
{
  int b = blockIdx.y;
  if (!(ab[8+b] > 0.5f)) return;
  float alpha = ab[b], beta = ab[4+b];
  float4* x4 = (float4*)(x + (size_t)b*NPIX);
  float4* r4 = (float4*)(r + (size_t)b*NPIX);
  float4* p4 = (float4*)(p + (size_t)b*NPIX);
  const float4* A4 = (const float4*)(Ap + (size_t)b*NPIX);
  for (int i = blockIdx.x*TPB + threadIdx.x; i < NPIX2; i += RED_BLKS*TPB) {
    float4 pv = p4[i], av = A4[i], xv = x4[i], rv = r4[i];
    xv.x += alpha*pv.x; xv.y += alpha*pv.y; xv.z += alpha*pv.z; xv.w += alpha*pv.w;
    rv.x -= alpha*av.x; rv.y -= alpha*av.y; rv.z -= alpha*av.z; rv.w -= alpha*av.w;
    x4[i] = xv; r4[i] = rv;
    p4[i] = make_float4(rv.x + beta*pv.x, rv.y + beta*pv.y,
                        rv.z + beta*pv.z, rv.w + beta*pv.w);
  }
}

// ---------------- launch ----------------

extern "C" void kernel_launch(void* const* d_in, const int* in_sizes, int n_in,
                              void* d_out, int out_size, void* d_ws, size_t ws_size,
                              hipStream_t stream)
{
  const float* lam  = (const float*)d_in[0];
  const float* xre  = (const float*)d_in[1];
  const float* xim  = (const float*)d_in[2];
  const float* yre  = (const float*)d_in[3];
  const float* yim  = (const float*)d_in[4];
  const float* sre  = (const float*)d_in[5];
  const float* sim  = (const float*)d_in[6];
  const float* mask = (const float*)d_in[7];

  const size_t szTmp  = (size_t)Bn*Cn*NPIX*sizeof(__half2);   // 37.7 MB
  const size_t szVec  = (size_t)Bn*NPIX*sizeof(float2);       // 4.7 MB
  const size_t szMask = (size_t)Bn*NPIX*sizeof(float);        // 2.4 MB
  const size_t szSh   = (size_t)Bn*Cn*NPIX*sizeof(__half2);   // 37.7 MB
  const size_t base   = szTmp + (size_t)GRP*szVec + 3*szVec + 2048 + szMask;
  const bool useSh    = (ws_size >= base + szSh);  // ws_size fixed -> stable path

  char* ws = (char*)d_ws;
  __half2* tmp = (__half2*)ws;  ws += szTmp;
  float2* part = (float2*)ws;   ws += (size_t)GRP*szVec;
  float2* r    = (float2*)ws;   ws += szVec;
  float2* p    = (float2*)ws;   ws += szVec;
  float2* Ap   = (float2*)ws;   ws += szVec;
  float*  scal = (float*)ws;    ws += 2048;
  float*  mskP = (float*)ws;    ws += szMask;
  __half2* Sh  = (__half2*)ws;
  float2* x    = (float2*)d_out;

  dim3 blk(TPB);
  dim3 rg(RED_BLKS, Bn);
  int grid_row = Bn*Cn*(Hn/8);       // 3072
  int grid_col = Bn*Cn*(Wn/NCOL);    // 1536
  int grid_inv = Bn*GRP*(Hn/8);      // 768

  k_maskp<<<(Bn*NPIX)/TPB, blk, 0, stream>>>(mask, mskP, scal);
  if (useSh)
    k_spack<<<(Bn*Cn*NPIX)/TPB, blk, 0, stream>>>(sre, sim, Sh);

  // ---- rhs = AH(y) + lambda*x ----
  k_col_rhs<<<grid_col, CTPB, 0, stream>>>(yre, yim, mask, tmp);
  k_row_inv_nat<<<grid_inv, blk, 0, stream>>>(tmp, sre, sim, part);
  k_rhs_init<<<rg, blk, 0, stream>>>(xre, xim, lam, part, r, p, x, scal);

  for (int it = 0; it < NITER; ++it) {
    if (useSh) {
      k_row_fwd<true><<<grid_row, blk, 0, stream>>>(p, sre, sim, Sh, tmp);
      k_col_full<<<grid_col, CTPB, 0, stream>>>(tmp, mskP);
      k_row_inv_scr<true><<<grid_inv, blk, 0, stream>>>(tmp, sre, sim, Sh, part);
    } else {
      k_row_fwd<false><<<grid_row, blk, 0, stream>>>(p, sre, sim, Sh, tmp);
      k_col_full<<<grid_col, CTPB, 0, stream>>>(tmp, mskP);
      k_row_inv_scr<false><<<grid_inv, blk, 0, stream>>>(tmp, sre, sim, Sh, part);
    }
    k_combine_dot3<<<rg, blk, 0, stream>>>(p, r, lam, part, Ap, scal + 64 + it*12);
    k_scal<<<1, 64, 0, stream>>>(scal, it);
    k_upd<<<rg, blk, 0, stream>>>(x, r, p, Ap, scal + 224 + it*12);
  }
}